// Round 3
// baseline (433.033 us; speedup 1.0000x reference)
//
#include <hip/hip_runtime.h>
#include <hip/hip_bf16.h>

using f32x4  = __attribute__((ext_vector_type(4))) float;
using i32x4  = __attribute__((ext_vector_type(4))) int;
using bf16x8 = __attribute__((ext_vector_type(8))) short;
using bf16x4 = __attribute__((ext_vector_type(4))) short;

constexpr int BATCH = 8, SEQ = 1024, DIM = 768, NHEAD = 12, HDIM = 64;
constexpr int MROWS = BATCH * SEQ;   // 8192

__device__ __forceinline__ short f2bf(float f) {
    union { float f; unsigned u; } x; x.f = f;
    unsigned r = (x.u + 0x7fffu + ((x.u >> 16) & 1u)) >> 16;
    return (short)r;
}
__device__ __forceinline__ float fexp2(float x) { return __builtin_amdgcn_exp2f(x); }

// C = A[M,K] @ W[DIM,K]^T + bias   (nn.Linear semantics, NT GEMM)
// OMODE: 0 = bf16 row-major, 1 = fp32 row-major, 2 = bf16 V^T per-head [B][H][HDIM][SEQ]
template <typename AT, int OMODE>
__global__ __launch_bounds__(256)
void gemm_bt(const AT* __restrict__ A, const float* __restrict__ W,
             const float* __restrict__ bias, void* __restrict__ Cout) {
    constexpr int K  = DIM;
    constexpr int NT = DIM / 128;  // 6 column tiles
    __shared__ short As[128][72];
    __shared__ short Bs[128][72];

    const int bm = blockIdx.x / NT, bn = blockIdx.x % NT;
    const int m0 = bm * 128, n0 = bn * 128;
    const int t = threadIdx.x;
    const int lane = t & 63, w = t >> 6;
    const int wm = (w >> 1) * 64, wn = (w & 1) * 64;
    const int l16 = lane & 15, lg = lane >> 4;

    const int sr = t >> 1, sc = (t & 1) * 16;   // staging: 16 elems/thread

    f32x4 acc[4][4] = {};

    for (int k0 = 0; k0 < K; k0 += 32) {
        __syncthreads();
        if constexpr (sizeof(AT) == 4) {
            const float* ap = (const float*)A + (long)(m0 + sr) * K + k0 + sc;
            float tmp[16];
            *(f32x4*)&tmp[0]  = *(const f32x4*)(ap + 0);
            *(f32x4*)&tmp[4]  = *(const f32x4*)(ap + 4);
            *(f32x4*)&tmp[8]  = *(const f32x4*)(ap + 8);
            *(f32x4*)&tmp[12] = *(const f32x4*)(ap + 12);
            short tb[16];
            #pragma unroll
            for (int j = 0; j < 16; ++j) tb[j] = f2bf(tmp[j]);
            *(bf16x8*)&As[sr][sc]     = *(bf16x8*)&tb[0];
            *(bf16x8*)&As[sr][sc + 8] = *(bf16x8*)&tb[8];
        } else {
            const short* ap = (const short*)A + (long)(m0 + sr) * K + k0 + sc;
            *(bf16x8*)&As[sr][sc]     = *(const bf16x8*)(ap);
            *(bf16x8*)&As[sr][sc + 8] = *(const bf16x8*)(ap + 8);
        }
        {
            const float* wp = W + (long)(n0 + sr) * K + k0 + sc;
            float tmp[16];
            *(f32x4*)&tmp[0]  = *(const f32x4*)(wp + 0);
            *(f32x4*)&tmp[4]  = *(const f32x4*)(wp + 4);
            *(f32x4*)&tmp[8]  = *(const f32x4*)(wp + 8);
            *(f32x4*)&tmp[12] = *(const f32x4*)(wp + 12);
            short tb[16];
            #pragma unroll
            for (int j = 0; j < 16; ++j) tb[j] = f2bf(tmp[j]);
            *(bf16x8*)&Bs[sr][sc]     = *(bf16x8*)&tb[0];
            *(bf16x8*)&Bs[sr][sc + 8] = *(bf16x8*)&tb[8];
        }
        __syncthreads();

        bf16x8 af[4], bfg[4];
        const int kc = lg * 8;
        #pragma unroll
        for (int mi = 0; mi < 4; ++mi)
            af[mi] = *(const bf16x8*)&As[wm + mi * 16 + l16][kc];
        #pragma unroll
        for (int ni = 0; ni < 4; ++ni)
            bfg[ni] = *(const bf16x8*)&Bs[wn + ni * 16 + l16][kc];
        #pragma unroll
        for (int mi = 0; mi < 4; ++mi)
            #pragma unroll
            for (int ni = 0; ni < 4; ++ni)
                acc[mi][ni] = __builtin_amdgcn_mfma_f32_16x16x32_bf16(
                    af[mi], bfg[ni], acc[mi][ni], 0, 0, 0);
    }

    // epilogue: C/D layout col=lane&15, row=(lane>>4)*4+j
    #pragma unroll
    for (int mi = 0; mi < 4; ++mi) {
        const int row = m0 + wm + mi * 16 + lg * 4;
        #pragma unroll
        for (int ni = 0; ni < 4; ++ni) {
            const int col = n0 + wn + ni * 16 + l16;
            const float bv = bias[col];
            #pragma unroll
            for (int j = 0; j < 4; ++j) {
                float val = acc[mi][ni][j] + bv;
                if constexpr (OMODE == 0) {
                    ((short*)Cout)[(long)(row + j) * DIM + col] = f2bf(val);
                } else if constexpr (OMODE == 1) {
                    ((float*)Cout)[(long)(row + j) * DIM + col] = val;
                } else {
                    // V^T per-head: [B][H][HDIM][SEQ]
                    const int bb = row / SEQ;
                    const int tok = (row % SEQ) + j;
                    const int hh = col >> 6, dd = col & 63;
                    ((short*)Cout)[((long)(bb * NHEAD + hh) * HDIM + dd) * SEQ + tok] = f2bf(val);
                }
            }
        }
    }
}

// Flash attention, swapped QK^T (mfma(K,Q)): each lane owns ONE q-row (l16)
// and 16 keys (c*16+lg*4+j). Bias/mask load as float4/int4 (coalesced),
// softmax in-register, P repacked via wave-local LDS. No block barriers.
__global__ __launch_bounds__(256)
void attn_kernel(const short* __restrict__ Qp, const short* __restrict__ Kp,
                 const short* __restrict__ Vt, const float* __restrict__ bias,
                 const int* __restrict__ mask, short* __restrict__ Op) {
    __shared__ short Ps[4][16][72];   // per-wave P^T-ish: [q local][key]

    const int bid = blockIdx.x;
    const int qt = bid & 15;                 // SEQ/64 q-tiles
    const int h  = (bid >> 4) % NHEAD;
    const int b  = bid / (16 * NHEAD);
    const int t = threadIdx.x;
    const int lane = t & 63, w = t >> 6;
    const int l16 = lane & 15, lg = lane >> 4;

    const int qrow = qt * 64 + w * 16 + l16;     // this lane's q-row
    const short* qptr = Qp + (long)(b * SEQ + qrow) * DIM + h * HDIM + lg * 8;
    const bf16x8 qf0 = *(const bf16x8*)qptr;
    const bf16x8 qf1 = *(const bf16x8*)(qptr + 32);

    const float* bias_row = bias + ((long)(b * NHEAD + h) * SEQ + qrow) * SEQ + lg * 4;
    const int*   mask_row = mask + ((long)b * SEQ + qrow) * SEQ + lg * 4;
    const short* kbase = Kp + (long)b * SEQ * DIM + h * HDIM + lg * 8;              // +key*DIM
    const short* vbase = Vt + ((long)(b * NHEAD + h) * HDIM + l16) * SEQ + lg * 8;  // +df*16*SEQ +kt*64

    f32x4 acc_o[4] = {};
    float m_run = -1e30f, l_run = 0.f;
    constexpr float L2E = 1.4426950408889634f;

    // prefetch bias/mask for kt=0
    f32x4 bias_n[4];
    i32x4 mask_n[4];
    #pragma unroll
    for (int c = 0; c < 4; ++c) {
        bias_n[c] = *(const f32x4*)(bias_row + c * 16);
        mask_n[c] = *(const i32x4*)(mask_row + c * 16);
    }

    for (int kt = 0; kt < SEQ / 64; ++kt) {
        // K fragments (used immediately by QK mfma)
        bf16x8 kb0[4], kb1[4];
        #pragma unroll
        for (int c = 0; c < 4; ++c) {
            const short* kp = kbase + (long)(kt * 64 + c * 16 + l16) * DIM;
            kb0[c] = *(const bf16x8*)kp;
            kb1[c] = *(const bf16x8*)(kp + 32);
        }
        // V fragments (used after softmax — issue early, latency hidden)
        bf16x8 vb0[4], vb1[4];
        #pragma unroll
        for (int df = 0; df < 4; ++df) {
            const short* vp = vbase + (long)df * 16 * SEQ + kt * 64;
            vb0[df] = *(const bf16x8*)vp;
            vb1[df] = *(const bf16x8*)(vp + 32);
        }

        // S^T = K Q^T : D row = key (lg*4+j within c*16), col = q (l16)
        f32x4 s[4];
        #pragma unroll
        for (int c = 0; c < 4; ++c) {
            f32x4 z = {};
            z    = __builtin_amdgcn_mfma_f32_16x16x32_bf16(kb0[c], qf0, z, 0, 0, 0);
            s[c] = __builtin_amdgcn_mfma_f32_16x16x32_bf16(kb1[c], qf1, z, 0, 0, 0);
        }

        // bias + mask from prefetched regs
        float p[4][4];
        float mt = -1e30f;
        #pragma unroll
        for (int c = 0; c < 4; ++c)
            #pragma unroll
            for (int j = 0; j < 4; ++j) {
                float sv = fmaf(s[c][j], 0.125f, bias_n[c][j]);
                sv = mask_n[c][j] ? sv : -1e30f;
                p[c][j] = sv;
                mt = fmaxf(mt, sv);
            }
        // prefetch bias/mask for next tile (regs now free)
        if (kt + 1 < SEQ / 64) {
            #pragma unroll
            for (int c = 0; c < 4; ++c) {
                bias_n[c] = *(const f32x4*)(bias_row + (kt + 1) * 64 + c * 16);
                mask_n[c] = *(const i32x4*)(mask_row + (kt + 1) * 64 + c * 16);
            }
        }

        // row-max across the 4 lg-groups holding this q-row
        mt = fmaxf(mt, __shfl_xor(mt, 16));
        mt = fmaxf(mt, __shfl_xor(mt, 32));
        const float mn = fmaxf(m_run, mt);
        const float alpha = fexp2((m_run - mn) * L2E);
        m_run = mn;
        const float nmL2 = -mn * L2E;

        float lt = 0.f;
        #pragma unroll
        for (int c = 0; c < 4; ++c)
            #pragma unroll
            for (int j = 0; j < 4; ++j) {
                const float e = fexp2(fmaf(p[c][j], L2E, nmL2));
                p[c][j] = e;
                lt += e;
            }
        lt += __shfl_xor(lt, 16);
        lt += __shfl_xor(lt, 32);
        l_run = l_run * alpha + lt;

        // broadcast alpha to PV C-layout rows (q = lg*4+j held by lane l16=q, lg=0)
        float al[4];
        #pragma unroll
        for (int j = 0; j < 4; ++j) al[j] = __shfl(alpha, lg * 4 + j);
        #pragma unroll
        for (int df = 0; df < 4; ++df)
            #pragma unroll
            for (int j = 0; j < 4; ++j)
                acc_o[df][j] *= al[j];

        // P -> LDS [q][key] via packed 8B writes (wave-local, no barrier)
        #pragma unroll
        for (int c = 0; c < 4; ++c) {
            bf16x4 pk;
            #pragma unroll
            for (int j = 0; j < 4; ++j) pk[j] = f2bf(p[c][j]);
            *(bf16x4*)&Ps[w][l16][c * 16 + lg * 4] = pk;
        }
        const bf16x8 pa0 = *(const bf16x8*)&Ps[w][l16][lg * 8];
        const bf16x8 pa1 = *(const bf16x8*)&Ps[w][l16][32 + lg * 8];

        #pragma unroll
        for (int df = 0; df < 4; ++df) {
            acc_o[df] = __builtin_amdgcn_mfma_f32_16x16x32_bf16(pa0, vb0[df], acc_o[df], 0, 0, 0);
            acc_o[df] = __builtin_amdgcn_mfma_f32_16x16x32_bf16(pa1, vb1[df], acc_o[df], 0, 0, 0);
        }
    }

    // epilogue: O /= l  (l for row lg*4+j lives in lane l16 = lg*4+j)
    float linv[4];
    #pragma unroll
    for (int j = 0; j < 4; ++j)
        linv[j] = 1.f / fmaxf(__shfl(l_run, lg * 4 + j), 1e-20f);

    #pragma unroll
    for (int df = 0; df < 4; ++df) {
        #pragma unroll
        for (int j = 0; j < 4; ++j) {
            const float val = acc_o[df][j] * linv[j];
            const int row = b * SEQ + qt * 64 + w * 16 + lg * 4 + j;
            const int col = h * HDIM + df * 16 + l16;
            Op[(long)row * DIM + col] = f2bf(val);
        }
    }
}

extern "C" void kernel_launch(void* const* d_in, const int* in_sizes, int n_in,
                              void* d_out, int out_size, void* d_ws, size_t ws_size,
                              hipStream_t stream) {
    const float* q         = (const float*)d_in[0];
    const float* k         = (const float*)d_in[1];
    const float* v         = (const float*)d_in[2];
    const float* attn_bias = (const float*)d_in[3];
    const int*   attn_mask = (const int*)d_in[4];
    const float* Wq = (const float*)d_in[5];
    const float* bq = (const float*)d_in[6];
    const float* Wk = (const float*)d_in[7];
    const float* bk = (const float*)d_in[8];
    const float* Wv = (const float*)d_in[9];
    const float* bv = (const float*)d_in[10];
    const float* Wo = (const float*)d_in[11];
    const float* bo = (const float*)d_in[12];
    float* out = (float*)d_out;

    short* Qp = (short*)d_ws;                    // [8192][768] bf16
    short* Kp = Qp + (long)MROWS * DIM;
    short* Vt = Kp + (long)MROWS * DIM;          // [B][H][64][1024] bf16
    short* Op = Vt + (long)MROWS * DIM;

    const dim3 blk(256);
    const int gemm_grid = (MROWS / 128) * (DIM / 128);   // 64*6 = 384

    gemm_bt<float, 0><<<gemm_grid, blk, 0, stream>>>(q, Wq, bq, Qp);
    gemm_bt<float, 0><<<gemm_grid, blk, 0, stream>>>(k, Wk, bk, Kp);
    gemm_bt<float, 2><<<gemm_grid, blk, 0, stream>>>(v, Wv, bv, Vt);

    const int attn_grid = BATCH * NHEAD * (SEQ / 64);    // 1536
    attn_kernel<<<attn_grid, blk, 0, stream>>>(Qp, Kp, Vt, attn_bias, attn_mask, Op);

    gemm_bt<short, 1><<<gemm_grid, blk, 0, stream>>>(Op, Wo, bo, out);
}

// Round 4
// 381.195 us; speedup vs baseline: 1.1360x; 1.1360x over previous
//
#include <hip/hip_runtime.h>
#include <hip/hip_bf16.h>

using f32x4  = __attribute__((ext_vector_type(4))) float;
using i32x4  = __attribute__((ext_vector_type(4))) int;
using bf16x8 = __attribute__((ext_vector_type(8))) short;
using bf16x4 = __attribute__((ext_vector_type(4))) short;

constexpr int BATCH = 8, SEQ = 1024, DIM = 768, NHEAD = 12, HDIM = 64;
constexpr int MROWS = BATCH * SEQ;   // 8192

__device__ __forceinline__ short f2bf(float f) {
    union { float f; unsigned u; } x; x.f = f;
    unsigned r = (x.u + 0x7fffu + ((x.u >> 16) & 1u)) >> 16;
    return (short)r;
}
__device__ __forceinline__ float fexp2(float x) { return __builtin_amdgcn_exp2f(x); }

// C = (A[M,K] @ W[DIM,K]^T + bias) * oscale
// OMODE: 0 = bf16 row-major, 1 = fp32 row-major, 2 = bf16 V^T per-head [B][H][HDIM][SEQ]
template <typename AT, int OMODE>
__global__ __launch_bounds__(256)
void gemm_bt(const AT* __restrict__ A, const float* __restrict__ W,
             const float* __restrict__ bias, void* __restrict__ Cout, float oscale) {
    constexpr int K  = DIM;
    constexpr int NT = DIM / 128;
    __shared__ short As[128][72];
    __shared__ short Bs[128][72];

    const int bm = blockIdx.x / NT, bn = blockIdx.x % NT;
    const int m0 = bm * 128, n0 = bn * 128;
    const int t = threadIdx.x;
    const int lane = t & 63, w = t >> 6;
    const int wm = (w >> 1) * 64, wn = (w & 1) * 64;
    const int l16 = lane & 15, lg = lane >> 4;

    const int sr = t >> 1, sc = (t & 1) * 16;

    f32x4 acc[4][4] = {};

    for (int k0 = 0; k0 < K; k0 += 32) {
        __syncthreads();
        if constexpr (sizeof(AT) == 4) {
            const float* ap = (const float*)A + (long)(m0 + sr) * K + k0 + sc;
            float tmp[16];
            *(f32x4*)&tmp[0]  = *(const f32x4*)(ap + 0);
            *(f32x4*)&tmp[4]  = *(const f32x4*)(ap + 4);
            *(f32x4*)&tmp[8]  = *(const f32x4*)(ap + 8);
            *(f32x4*)&tmp[12] = *(const f32x4*)(ap + 12);
            short tb[16];
            #pragma unroll
            for (int j = 0; j < 16; ++j) tb[j] = f2bf(tmp[j]);
            *(bf16x8*)&As[sr][sc]     = *(bf16x8*)&tb[0];
            *(bf16x8*)&As[sr][sc + 8] = *(bf16x8*)&tb[8];
        } else {
            const short* ap = (const short*)A + (long)(m0 + sr) * K + k0 + sc;
            *(bf16x8*)&As[sr][sc]     = *(const bf16x8*)(ap);
            *(bf16x8*)&As[sr][sc + 8] = *(const bf16x8*)(ap + 8);
        }
        {
            const float* wp = W + (long)(n0 + sr) * K + k0 + sc;
            float tmp[16];
            *(f32x4*)&tmp[0]  = *(const f32x4*)(wp + 0);
            *(f32x4*)&tmp[4]  = *(const f32x4*)(wp + 4);
            *(f32x4*)&tmp[8]  = *(const f32x4*)(wp + 8);
            *(f32x4*)&tmp[12] = *(const f32x4*)(wp + 12);
            short tb[16];
            #pragma unroll
            for (int j = 0; j < 16; ++j) tb[j] = f2bf(tmp[j]);
            *(bf16x8*)&Bs[sr][sc]     = *(bf16x8*)&tb[0];
            *(bf16x8*)&Bs[sr][sc + 8] = *(bf16x8*)&tb[8];
        }
        __syncthreads();

        bf16x8 af[4], bfg[4];
        const int kc = lg * 8;
        #pragma unroll
        for (int mi = 0; mi < 4; ++mi)
            af[mi] = *(const bf16x8*)&As[wm + mi * 16 + l16][kc];
        #pragma unroll
        for (int ni = 0; ni < 4; ++ni)
            bfg[ni] = *(const bf16x8*)&Bs[wn + ni * 16 + l16][kc];
        #pragma unroll
        for (int mi = 0; mi < 4; ++mi)
            #pragma unroll
            for (int ni = 0; ni < 4; ++ni)
                acc[mi][ni] = __builtin_amdgcn_mfma_f32_16x16x32_bf16(
                    af[mi], bfg[ni], acc[mi][ni], 0, 0, 0);
    }

    #pragma unroll
    for (int mi = 0; mi < 4; ++mi) {
        const int row = m0 + wm + mi * 16 + lg * 4;
        #pragma unroll
        for (int ni = 0; ni < 4; ++ni) {
            const int col = n0 + wn + ni * 16 + l16;
            const float bv = bias[col];
            #pragma unroll
            for (int j = 0; j < 4; ++j) {
                float val = (acc[mi][ni][j] + bv) * oscale;
                if constexpr (OMODE == 0) {
                    ((short*)Cout)[(long)(row + j) * DIM + col] = f2bf(val);
                } else if constexpr (OMODE == 1) {
                    ((float*)Cout)[(long)(row + j) * DIM + col] = val;
                } else {
                    const int bb = row / SEQ;
                    const int tok = (row % SEQ) + j;
                    const int hh = col >> 6, dd = col & 63;
                    ((short*)Cout)[((long)(bb * NHEAD + hh) * HDIM + dd) * SEQ + tok] = f2bf(val);
                }
            }
        }
    }
}

// Flash attention, swapped QK^T. Bias+mask staged per-tile through LDS with
// block-cooperative CONTIGUOUS loads (4x256B segments per wave instr instead of
// 16x64B), fused mask, bias enters as MFMA C-init. Scale folded into Q proj.
__global__ __launch_bounds__(256)
void attn_kernel(const short* __restrict__ Qp, const short* __restrict__ Kp,
                 const short* __restrict__ Vt, const float* __restrict__ bias,
                 const int* __restrict__ mask, short* __restrict__ Op) {
    __shared__ float Bsm[64][68];     // masked bias tile [q_local][k_local], 17.4 KB
    __shared__ short Ps[4][16][72];   // per-wave P, 9.2 KB

    const int bid = blockIdx.x;
    const int qt = bid & 15, h = (bid >> 4) % NHEAD, b = bid / (16 * NHEAD);
    const int t = threadIdx.x, lane = t & 63, w = t >> 6;
    const int l16 = lane & 15, lg = lane >> 4;
    const int ql = w * 16 + l16;             // this lane's q within the 64-row tile

    const int qrow = qt * 64 + ql;
    const short* qptr = Qp + (long)(b * SEQ + qrow) * DIM + h * HDIM + lg * 8;
    const bf16x8 qf0 = *(const bf16x8*)qptr;
    const bf16x8 qf1 = *(const bf16x8*)(qptr + 32);

    const short* kbase = Kp + (long)b * SEQ * DIM + h * HDIM + lg * 8;
    const short* vbase = Vt + ((long)(b * NHEAD + h) * HDIM + l16) * SEQ + lg * 8;

    // staging map: thread t covers rows i*16 + (t>>4), cols (t&15)*4..+3 (+kt*64)
    const int srow = t >> 4, scol = (t & 15) * 4;
    const float* bst = bias + ((long)(b * NHEAD + h) * SEQ + qt * 64 + srow) * SEQ + scol;
    const int*   mst = mask + ((long)b * SEQ + qt * 64 + srow) * SEQ + scol;

    f32x4 acc_o[4] = {};
    float m_run = -1e30f, l_run = 0.f;
    constexpr float L2E = 1.4426950408889634f;

    {   // prologue: stage tile 0
        f32x4 br[4]; i32x4 mr[4];
        #pragma unroll
        for (int i = 0; i < 4; ++i) {
            br[i] = *(const f32x4*)(bst + (long)i * 16 * SEQ);
            mr[i] = *(const i32x4*)(mst + (long)i * 16 * SEQ);
        }
        #pragma unroll
        for (int i = 0; i < 4; ++i) {
            f32x4 o;
            #pragma unroll
            for (int j = 0; j < 4; ++j) o[j] = mr[i][j] ? br[i][j] : -1e30f;
            *(f32x4*)&Bsm[i * 16 + srow][scol] = o;
        }
    }
    __syncthreads();

    for (int kt = 0; kt < SEQ / 64; ++kt) {
        // prefetch next tile's bias/mask to registers (landed by barrier time)
        f32x4 br[4]; i32x4 mr[4];
        if (kt < 15) {
            #pragma unroll
            for (int i = 0; i < 4; ++i) {
                br[i] = *(const f32x4*)(bst + (long)i * 16 * SEQ + (kt + 1) * 64);
                mr[i] = *(const i32x4*)(mst + (long)i * 16 * SEQ + (kt + 1) * 64);
            }
        }

        // QK^T with C initialized to masked bias (scale already folded into Q)
        f32x4 s[4];
        #pragma unroll
        for (int c = 0; c < 4; ++c) {
            const short* kp = kbase + (long)(kt * 64 + c * 16 + l16) * DIM;
            const bf16x8 kb0 = *(const bf16x8*)kp;
            const bf16x8 kb1 = *(const bf16x8*)(kp + 32);
            f32x4 ci = *(const f32x4*)&Bsm[ql][c * 16 + lg * 4];
            ci   = __builtin_amdgcn_mfma_f32_16x16x32_bf16(kb0, qf0, ci, 0, 0, 0);
            s[c] = __builtin_amdgcn_mfma_f32_16x16x32_bf16(kb1, qf1, ci, 0, 0, 0);
        }

        // V fragments (issue now, consumed after softmax)
        bf16x8 vb0[4], vb1[4];
        #pragma unroll
        for (int df = 0; df < 4; ++df) {
            const short* vp = vbase + (long)df * 16 * SEQ + kt * 64;
            vb0[df] = *(const bf16x8*)vp;
            vb1[df] = *(const bf16x8*)(vp + 32);
        }

        // online softmax (bias+mask already inside s)
        float mt = -1e30f;
        #pragma unroll
        for (int c = 0; c < 4; ++c)
            #pragma unroll
            for (int j = 0; j < 4; ++j)
                mt = fmaxf(mt, s[c][j]);
        mt = fmaxf(mt, __shfl_xor(mt, 16));
        mt = fmaxf(mt, __shfl_xor(mt, 32));
        const float mn = fmaxf(m_run, mt);
        const float alpha = fexp2((m_run - mn) * L2E);
        m_run = mn;
        const float nm = -mn * L2E;

        float lt = 0.f;
        #pragma unroll
        for (int c = 0; c < 4; ++c) {
            bf16x4 pk;
            #pragma unroll
            for (int j = 0; j < 4; ++j) {
                const float e = fexp2(fmaf(s[c][j], L2E, nm));
                lt += e;
                pk[j] = f2bf(e);
            }
            *(bf16x4*)&Ps[w][l16][c * 16 + lg * 4] = pk;
        }
        lt += __shfl_xor(lt, 16);
        lt += __shfl_xor(lt, 32);
        l_run = l_run * alpha + lt;

        float al[4];
        #pragma unroll
        for (int j = 0; j < 4; ++j) al[j] = __shfl(alpha, lg * 4 + j);
        #pragma unroll
        for (int df = 0; df < 4; ++df)
            #pragma unroll
            for (int j = 0; j < 4; ++j)
                acc_o[df][j] *= al[j];

        const bf16x8 pa0 = *(const bf16x8*)&Ps[w][l16][lg * 8];
        const bf16x8 pa1 = *(const bf16x8*)&Ps[w][l16][32 + lg * 8];

        #pragma unroll
        for (int df = 0; df < 4; ++df) {
            acc_o[df] = __builtin_amdgcn_mfma_f32_16x16x32_bf16(pa0, vb0[df], acc_o[df], 0, 0, 0);
            acc_o[df] = __builtin_amdgcn_mfma_f32_16x16x32_bf16(pa1, vb1[df], acc_o[df], 0, 0, 0);
        }

        // stage next tile
        if (kt < 15) {
            __syncthreads();          // everyone done reading Bsm for kt
            #pragma unroll
            for (int i = 0; i < 4; ++i) {
                f32x4 o;
                #pragma unroll
                for (int j = 0; j < 4; ++j) o[j] = mr[i][j] ? br[i][j] : -1e30f;
                *(f32x4*)&Bsm[i * 16 + srow][scol] = o;
            }
            __syncthreads();          // Bsm ready for kt+1
        }
    }

    // epilogue
    float linv[4];
    #pragma unroll
    for (int j = 0; j < 4; ++j)
        linv[j] = 1.f / fmaxf(__shfl(l_run, lg * 4 + j), 1e-20f);

    #pragma unroll
    for (int df = 0; df < 4; ++df) {
        #pragma unroll
        for (int j = 0; j < 4; ++j) {
            const float val = acc_o[df][j] * linv[j];
            const int row = b * SEQ + qt * 64 + lg * 4 + j + w * 16;
            const int col = h * HDIM + df * 16 + l16;
            Op[(long)(b * SEQ + qt * 64 + w * 16 + lg * 4 + j) * DIM + col] = f2bf(val);
            (void)row;
        }
    }
}

extern "C" void kernel_launch(void* const* d_in, const int* in_sizes, int n_in,
                              void* d_out, int out_size, void* d_ws, size_t ws_size,
                              hipStream_t stream) {
    const float* q         = (const float*)d_in[0];
    const float* k         = (const float*)d_in[1];
    const float* v         = (const float*)d_in[2];
    const float* attn_bias = (const float*)d_in[3];
    const int*   attn_mask = (const int*)d_in[4];
    const float* Wq = (const float*)d_in[5];
    const float* bq = (const float*)d_in[6];
    const float* Wk = (const float*)d_in[7];
    const float* bk = (const float*)d_in[8];
    const float* Wv = (const float*)d_in[9];
    const float* bv = (const float*)d_in[10];
    const float* Wo = (const float*)d_in[11];
    const float* bo = (const float*)d_in[12];
    float* out = (float*)d_out;

    short* Qp = (short*)d_ws;                    // [8192][768] bf16 (pre-scaled by 0.125)
    short* Kp = Qp + (long)MROWS * DIM;
    short* Vt = Kp + (long)MROWS * DIM;          // [B][H][64][1024] bf16
    short* Op = Vt + (long)MROWS * DIM;

    const dim3 blk(256);
    const int gemm_grid = (MROWS / 128) * (DIM / 128);   // 384

    gemm_bt<float, 0><<<gemm_grid, blk, 0, stream>>>(q, Wq, bq, Qp, 0.125f);
    gemm_bt<float, 0><<<gemm_grid, blk, 0, stream>>>(k, Wk, bk, Kp, 1.0f);
    gemm_bt<float, 2><<<gemm_grid, blk, 0, stream>>>(v, Wv, bv, Vt, 1.0f);

    const int attn_grid = BATCH * NHEAD * (SEQ / 64);    // 1536
    attn_kernel<<<attn_grid, blk, 0, stream>>>(Qp, Kp, Vt, attn_bias, attn_mask, Op);

    gemm_bt<short, 1><<<gemm_grid, blk, 0, stream>>>(Op, Wo, bo, out, 1.0f);
}

// Round 5
// 292.401 us; speedup vs baseline: 1.4810x; 1.3037x over previous
//
#include <hip/hip_runtime.h>
#include <hip/hip_bf16.h>

using f32x4  = __attribute__((ext_vector_type(4))) float;
using i32x4  = __attribute__((ext_vector_type(4))) int;
using bf16x8 = __attribute__((ext_vector_type(8))) short;
using bf16x4 = __attribute__((ext_vector_type(4))) short;

constexpr int BATCH = 8, SEQ = 1024, DIM = 768, NHEAD = 12, HDIM = 64;
constexpr int MROWS = BATCH * SEQ;   // 8192

__device__ __forceinline__ short f2bf(float f) {
    union { float f; unsigned u; } x; x.f = f;
    unsigned r = (x.u + 0x7fffu + ((x.u >> 16) & 1u)) >> 16;
    return (short)r;
}
__device__ __forceinline__ float fexp2(float x) { return __builtin_amdgcn_exp2f(x); }

// C = (A[M,K] @ W[DIM,K]^T + bias) * oscale
// OMODE: 0 = bf16 row-major            1 = fp32 row-major
//        2 = V tiled [b*H+h][kt][hd][key]   3 = K tiled [b*H+h][kt][key][hd]
template <typename AT, int OMODE>
__global__ __launch_bounds__(256)
void gemm_bt(const AT* __restrict__ A, const float* __restrict__ W,
             const float* __restrict__ bias, void* __restrict__ Cout, float oscale) {
    constexpr int K  = DIM;
    constexpr int NT = DIM / 128;
    __shared__ short As[128][72];
    __shared__ short Bs[128][72];

    const int bm = blockIdx.x / NT, bn = blockIdx.x % NT;
    const int m0 = bm * 128, n0 = bn * 128;
    const int t = threadIdx.x;
    const int lane = t & 63, w = t >> 6;
    const int wm = (w >> 1) * 64, wn = (w & 1) * 64;
    const int l16 = lane & 15, lg = lane >> 4;

    const int sr = t >> 1, sc = (t & 1) * 16;

    f32x4 acc[4][4] = {};

    for (int k0 = 0; k0 < K; k0 += 32) {
        __syncthreads();
        if constexpr (sizeof(AT) == 4) {
            const float* ap = (const float*)A + (long)(m0 + sr) * K + k0 + sc;
            float tmp[16];
            *(f32x4*)&tmp[0]  = *(const f32x4*)(ap + 0);
            *(f32x4*)&tmp[4]  = *(const f32x4*)(ap + 4);
            *(f32x4*)&tmp[8]  = *(const f32x4*)(ap + 8);
            *(f32x4*)&tmp[12] = *(const f32x4*)(ap + 12);
            short tb[16];
            #pragma unroll
            for (int j = 0; j < 16; ++j) tb[j] = f2bf(tmp[j]);
            *(bf16x8*)&As[sr][sc]     = *(bf16x8*)&tb[0];
            *(bf16x8*)&As[sr][sc + 8] = *(bf16x8*)&tb[8];
        } else {
            const short* ap = (const short*)A + (long)(m0 + sr) * K + k0 + sc;
            *(bf16x8*)&As[sr][sc]     = *(const bf16x8*)(ap);
            *(bf16x8*)&As[sr][sc + 8] = *(const bf16x8*)(ap + 8);
        }
        {
            const float* wp = W + (long)(n0 + sr) * K + k0 + sc;
            float tmp[16];
            *(f32x4*)&tmp[0]  = *(const f32x4*)(wp + 0);
            *(f32x4*)&tmp[4]  = *(const f32x4*)(wp + 4);
            *(f32x4*)&tmp[8]  = *(const f32x4*)(wp + 8);
            *(f32x4*)&tmp[12] = *(const f32x4*)(wp + 12);
            short tb[16];
            #pragma unroll
            for (int j = 0; j < 16; ++j) tb[j] = f2bf(tmp[j]);
            *(bf16x8*)&Bs[sr][sc]     = *(bf16x8*)&tb[0];
            *(bf16x8*)&Bs[sr][sc + 8] = *(bf16x8*)&tb[8];
        }
        __syncthreads();

        bf16x8 af[4], bfg[4];
        const int kc = lg * 8;
        #pragma unroll
        for (int mi = 0; mi < 4; ++mi)
            af[mi] = *(const bf16x8*)&As[wm + mi * 16 + l16][kc];
        #pragma unroll
        for (int ni = 0; ni < 4; ++ni)
            bfg[ni] = *(const bf16x8*)&Bs[wn + ni * 16 + l16][kc];
        #pragma unroll
        for (int mi = 0; mi < 4; ++mi)
            #pragma unroll
            for (int ni = 0; ni < 4; ++ni)
                acc[mi][ni] = __builtin_amdgcn_mfma_f32_16x16x32_bf16(
                    af[mi], bfg[ni], acc[mi][ni], 0, 0, 0);
    }

    #pragma unroll
    for (int mi = 0; mi < 4; ++mi) {
        const int row = m0 + wm + mi * 16 + lg * 4;
        #pragma unroll
        for (int ni = 0; ni < 4; ++ni) {
            const int col = n0 + wn + ni * 16 + l16;
            const float bv = bias[col];
            #pragma unroll
            for (int j = 0; j < 4; ++j) {
                float val = (acc[mi][ni][j] + bv) * oscale;
                if constexpr (OMODE == 0) {
                    ((short*)Cout)[(long)(row + j) * DIM + col] = f2bf(val);
                } else if constexpr (OMODE == 1) {
                    ((float*)Cout)[(long)(row + j) * DIM + col] = val;
                } else {
                    const int bb = row / SEQ;
                    const int tok = (row % SEQ) + j;
                    const int hh = col >> 6, dd = col & 63;
                    const long base = ((long)(bb * NHEAD + hh) * 16 + (tok >> 6)) * 4096;
                    if constexpr (OMODE == 2)
                        ((short*)Cout)[base + dd * 64 + (tok & 63)] = f2bf(val);  // V^T tile
                    else
                        ((short*)Cout)[base + (tok & 63) * 64 + dd] = f2bf(val);  // K tile
                }
            }
        }
    }
}

// Flash attention. K/V staged to LDS from contiguous 8KB tiles (coalesced),
// bias+mask staged to LDS (contiguous), bias as MFMA C-init, in-reg softmax.
// T14: next-tile global loads issued before compute, LDS writes after barrier.
__global__ __launch_bounds__(256)
void attn_kernel(const short* __restrict__ Qp, const short* __restrict__ Kt,
                 const short* __restrict__ Vt, const float* __restrict__ bias,
                 const int* __restrict__ mask, short* __restrict__ Op) {
    __shared__ float Bsm[64][68];     // masked bias [q][k]   17.4 KB
    __shared__ short Ks[64][72];      // K tile [key][hd]      9.2 KB
    __shared__ short Vs[64][72];      // V^T tile [hd][key]    9.2 KB
    __shared__ short Ps[4][16][72];   // per-wave P            9.2 KB

    // XCD remap: all 16 q-tiles of one (b,h) pair on one XCD (idx%8 heuristic)
    const int d = blockIdx.x;
    const int lgc = (d & 7) * 192 + (d >> 3);
    const int qt = lgc & 15, pair = lgc >> 4;          // pair = b*NHEAD+h
    const int h = pair % NHEAD, b = pair / NHEAD;

    const int t = threadIdx.x, lane = t & 63, w = t >> 6;
    const int l16 = lane & 15, lg = lane >> 4;
    const int ql = w * 16 + l16;

    const int qrow = qt * 64 + ql;
    const short* qptr = Qp + (long)(b * SEQ + qrow) * DIM + h * HDIM + lg * 8;
    const bf16x8 qf0 = *(const bf16x8*)qptr;
    const bf16x8 qf1 = *(const bf16x8*)(qptr + 32);

    const short* ktile = Kt + (long)pair * 16 * 4096;
    const short* vtile = Vt + (long)pair * 16 * 4096;

    // bias/mask staging map: rows i*16 + (t>>4), cols (t&15)*4
    const int srow = t >> 4, scol = (t & 15) * 4;
    const float* bst = bias + ((long)pair * SEQ + qt * 64 + srow) * SEQ + scol;
    const int*   mst = mask + ((long)b * SEQ + qt * 64 + srow) * SEQ + scol;

    // K/V staging map: slot t -> row t>>3, col (t&7)*8; second load row +32
    const int kr = t >> 3, kc = (t & 7) * 8;

    f32x4 acc_o[4] = {};
    float m_run = -1e30f, l_run = 0.f;
    constexpr float L2E = 1.4426950408889634f;

    // staging registers
    f32x4 br[4]; i32x4 mr[4]; bf16x8 kst0, kst1, vst0, vst1;

    {   // prologue: load + write tile 0
        #pragma unroll
        for (int i = 0; i < 4; ++i) {
            br[i] = *(const f32x4*)(bst + (long)i * 16 * SEQ);
            mr[i] = *(const i32x4*)(mst + (long)i * 16 * SEQ);
        }
        kst0 = *(const bf16x8*)(ktile + t * 8);
        kst1 = *(const bf16x8*)(ktile + t * 8 + 2048);
        vst0 = *(const bf16x8*)(vtile + t * 8);
        vst1 = *(const bf16x8*)(vtile + t * 8 + 2048);
        #pragma unroll
        for (int i = 0; i < 4; ++i) {
            f32x4 o;
            #pragma unroll
            for (int j = 0; j < 4; ++j) o[j] = mr[i][j] ? br[i][j] : -1e30f;
            *(f32x4*)&Bsm[i * 16 + srow][scol] = o;
        }
        *(bf16x8*)&Ks[kr][kc]      = kst0;
        *(bf16x8*)&Ks[kr + 32][kc] = kst1;
        *(bf16x8*)&Vs[kr][kc]      = vst0;
        *(bf16x8*)&Vs[kr + 32][kc] = vst1;
    }
    __syncthreads();

    for (int kt = 0; kt < 16; ++kt) {
        // T14 issue-early: next tile's global loads
        if (kt < 15) {
            #pragma unroll
            for (int i = 0; i < 4; ++i) {
                br[i] = *(const f32x4*)(bst + (long)i * 16 * SEQ + (kt + 1) * 64);
                mr[i] = *(const i32x4*)(mst + (long)i * 16 * SEQ + (kt + 1) * 64);
            }
            const short* kp = ktile + (kt + 1) * 4096 + t * 8;
            const short* vp = vtile + (kt + 1) * 4096 + t * 8;
            kst0 = *(const bf16x8*)kp;
            kst1 = *(const bf16x8*)(kp + 2048);
            vst0 = *(const bf16x8*)vp;
            vst1 = *(const bf16x8*)(vp + 2048);
        }

        // QK^T from LDS, bias C-init
        f32x4 s[4];
        #pragma unroll
        for (int c = 0; c < 4; ++c) {
            const bf16x8 kb0 = *(const bf16x8*)&Ks[c * 16 + l16][lg * 8];
            const bf16x8 kb1 = *(const bf16x8*)&Ks[c * 16 + l16][32 + lg * 8];
            f32x4 ci = *(const f32x4*)&Bsm[ql][c * 16 + lg * 4];
            ci   = __builtin_amdgcn_mfma_f32_16x16x32_bf16(kb0, qf0, ci, 0, 0, 0);
            s[c] = __builtin_amdgcn_mfma_f32_16x16x32_bf16(kb1, qf1, ci, 0, 0, 0);
        }

        // V fragments from LDS
        bf16x8 vb0[4], vb1[4];
        #pragma unroll
        for (int df = 0; df < 4; ++df) {
            vb0[df] = *(const bf16x8*)&Vs[df * 16 + l16][lg * 8];
            vb1[df] = *(const bf16x8*)&Vs[df * 16 + l16][32 + lg * 8];
        }

        // online softmax
        float mt = -1e30f;
        #pragma unroll
        for (int c = 0; c < 4; ++c)
            #pragma unroll
            for (int j = 0; j < 4; ++j)
                mt = fmaxf(mt, s[c][j]);
        mt = fmaxf(mt, __shfl_xor(mt, 16));
        mt = fmaxf(mt, __shfl_xor(mt, 32));
        const float mn = fmaxf(m_run, mt);
        const float alpha = fexp2((m_run - mn) * L2E);
        m_run = mn;
        const float nm = -mn * L2E;

        float lt = 0.f;
        #pragma unroll
        for (int c = 0; c < 4; ++c) {
            bf16x4 pk;
            #pragma unroll
            for (int j = 0; j < 4; ++j) {
                const float e = fexp2(fmaf(s[c][j], L2E, nm));
                lt += e;
                pk[j] = f2bf(e);
            }
            *(bf16x4*)&Ps[w][l16][c * 16 + lg * 4] = pk;
        }
        lt += __shfl_xor(lt, 16);
        lt += __shfl_xor(lt, 32);
        l_run = l_run * alpha + lt;

        float al[4];
        #pragma unroll
        for (int j = 0; j < 4; ++j) al[j] = __shfl(alpha, lg * 4 + j);
        #pragma unroll
        for (int df = 0; df < 4; ++df)
            #pragma unroll
            for (int j = 0; j < 4; ++j)
                acc_o[df][j] *= al[j];

        const bf16x8 pa0 = *(const bf16x8*)&Ps[w][l16][lg * 8];
        const bf16x8 pa1 = *(const bf16x8*)&Ps[w][l16][32 + lg * 8];

        #pragma unroll
        for (int df = 0; df < 4; ++df) {
            acc_o[df] = __builtin_amdgcn_mfma_f32_16x16x32_bf16(pa0, vb0[df], acc_o[df], 0, 0, 0);
            acc_o[df] = __builtin_amdgcn_mfma_f32_16x16x32_bf16(pa1, vb1[df], acc_o[df], 0, 0, 0);
        }

        // T14 write-late: staged regs -> LDS
        if (kt < 15) {
            __syncthreads();
            #pragma unroll
            for (int i = 0; i < 4; ++i) {
                f32x4 o;
                #pragma unroll
                for (int j = 0; j < 4; ++j) o[j] = mr[i][j] ? br[i][j] : -1e30f;
                *(f32x4*)&Bsm[i * 16 + srow][scol] = o;
            }
            *(bf16x8*)&Ks[kr][kc]      = kst0;
            *(bf16x8*)&Ks[kr + 32][kc] = kst1;
            *(bf16x8*)&Vs[kr][kc]      = vst0;
            *(bf16x8*)&Vs[kr + 32][kc] = vst1;
            __syncthreads();
        }
    }

    // epilogue
    float linv[4];
    #pragma unroll
    for (int j = 0; j < 4; ++j)
        linv[j] = 1.f / fmaxf(__shfl(l_run, lg * 4 + j), 1e-20f);

    #pragma unroll
    for (int df = 0; df < 4; ++df) {
        #pragma unroll
        for (int j = 0; j < 4; ++j) {
            const float val = acc_o[df][j] * linv[j];
            const int row = b * SEQ + qt * 64 + w * 16 + lg * 4 + j;
            const int col = h * HDIM + df * 16 + l16;
            Op[(long)row * DIM + col] = f2bf(val);
        }
    }
}

extern "C" void kernel_launch(void* const* d_in, const int* in_sizes, int n_in,
                              void* d_out, int out_size, void* d_ws, size_t ws_size,
                              hipStream_t stream) {
    const float* q         = (const float*)d_in[0];
    const float* k         = (const float*)d_in[1];
    const float* v         = (const float*)d_in[2];
    const float* attn_bias = (const float*)d_in[3];
    const int*   attn_mask = (const int*)d_in[4];
    const float* Wq = (const float*)d_in[5];
    const float* bq = (const float*)d_in[6];
    const float* Wk = (const float*)d_in[7];
    const float* bk = (const float*)d_in[8];
    const float* Wv = (const float*)d_in[9];
    const float* bv = (const float*)d_in[10];
    const float* Wo = (const float*)d_in[11];
    const float* bo = (const float*)d_in[12];
    float* out = (float*)d_out;

    short* Qp = (short*)d_ws;                    // [8192][768] bf16 (pre-scaled 0.125)
    short* Kp = Qp + (long)MROWS * DIM;          // K tiled [96][16][64][64]
    short* Vp = Kp + (long)MROWS * DIM;          // V tiled [96][16][64][64] (hd-major)
    short* Op = Vp + (long)MROWS * DIM;

    const dim3 blk(256);
    const int gemm_grid = (MROWS / 128) * (DIM / 128);   // 384

    gemm_bt<float, 0><<<gemm_grid, blk, 0, stream>>>(q, Wq, bq, Qp, 0.125f);
    gemm_bt<float, 3><<<gemm_grid, blk, 0, stream>>>(k, Wk, bk, Kp, 1.0f);
    gemm_bt<float, 2><<<gemm_grid, blk, 0, stream>>>(v, Wv, bv, Vp, 1.0f);

    const int attn_grid = BATCH * NHEAD * (SEQ / 64);    // 1536
    attn_kernel<<<attn_grid, blk, 0, stream>>>(Qp, Kp, Vp, attn_bias, attn_mask, Op);

    gemm_bt<short, 1><<<gemm_grid, blk, 0, stream>>>(Op, Wo, bo, out, 1.0f);
}